// Round 10
// baseline (792.358 us; speedup 1.0000x reference)
//
#include <hip/hip_runtime.h>

// SLAYER SNN forward, round 25 = round 24 with the VGPR spill removed.
// RE-ATTRIBUTION: r23/r24's FETCH+WRITE blowups (300-385MB vs 37MB logical,
// pipes idle) were SCRATCH SPILL, not store RMW: af[14](56 VGPR)+acc[6](24)
// exceeded the 128-VGPR allocation; spill round-trips invented HBM write
// traffic and thrashed per-XCD L2 so the A-loads missed too. r22 (88 VGPR)
// never spilled.
//  - conv_mfma_b (L3, L5): r24's conv_mfma_s with the kc loop BLOCKED in
//    chunks of KCB=7 fragments: af[7] = 28 VGPR live instead of 56. Live set
//    ~80 VGPR -> no spill. Per-output accumulation order p{kc 0..KC-1} is
//    bit-identical to r22/r24 (both absmax 0). Store path unchanged (cst LDS
//    staging + float4 streaming -- r22-proven full-line writes).
//  - conv_mfma_d (L1) unchanged. All else identical to r24.
// All fp32 elsewhere; IIR op ordering bit-matches the reference scan.

#define TT 300

#define A1 0.9048374180359595f   // exp(-1/10)
#define C1 0.2718281828459045f   // e/10
#define A2 0.36787944117144233f  // exp(-1)
#define C2 2.718281828459045f    // e
#define KREF (20.0f * C2)
#define THETA_F 10.0f

typedef float v2f __attribute__((ext_vector_type(2)));
typedef float f32x4 __attribute__((ext_vector_type(4)));
typedef short bf16x8 __attribute__((ext_vector_type(8)));

struct IIR {
  float p1, q1, p2, q2;
  __device__ IIR() : p1(0.f), q1(0.f), p2(0.f), q2(0.f) {}
  __device__ inline float step(float xin) {
    q1 = A1 * q1 + A1 * p1;
    float y = C1 * q1;
    p1 = A1 * p1 + xin;
    q2 = A2 * q2 + A2 * p2;
    float u = y - KREF * q2;
    float s = (u >= THETA_F) ? 1.0f : 0.0f;
    p2 = A2 * p2 + s;
    return s;
  }
};

// ---------------- generic tiled transpose: in[R][C] -> out[C][R] ----------------
__global__ __launch_bounds__(256) void transpose_rc(const float* __restrict__ in,
                                                    float* __restrict__ out,
                                                    int R, int C) {
  __shared__ float tile[64][65];
  int c0 = blockIdx.x * 64, r0 = blockIdx.y * 64;
  int tx = threadIdx.x & 63, ty = threadIdx.x >> 6;
  for (int i = ty; i < 64; i += 4) {
    int r = r0 + i, c = c0 + tx;
    if (r < R && c < C) tile[i][tx] = in[(long)r * C + c];
  }
  __syncthreads();
  for (int i = ty; i < 64; i += 4) {
    int c = c0 + i, r = r0 + tx;
    if (c < C && r < R) out[(long)c * R + r] = tile[tx][i];
  }
}

// ---------------- prep_mfma: 3-plane exact bf16 split, fragment-major ----------
// Wm[p][m][kc][lane][e] ushort; co = m*16 + (lane&15); k = kc*32+(lane>>4)*8+e;
// k>=K or co>=CO -> exact 0 in all planes (lets conv skip B-side guards).
__device__ inline unsigned rne_bf16_bits(float f) {
  unsigned u = __float_as_uint(f);
  return (u + 0x7FFFu + ((u >> 16) & 1u)) >> 16;
}
template <int CIN, int KS, int CO, int MT, int KC>
__global__ __launch_bounds__(256) void prep_mfma(const float* __restrict__ Wc,
                                                 ushort* __restrict__ Wm) {
  constexpr int K = CIN * KS * KS;
  constexpr int PLANE = MT * KC * 512;
  int i = blockIdx.x * 256 + threadIdx.x;
  if (i >= PLANE) return;
  int e = i & 7, l = (i >> 3) & 63;
  int rest = i >> 9;
  int kc = rest % KC, m = rest / KC;
  int co = m * 16 + (l & 15);
  int k = kc * 32 + (l >> 4) * 8 + e;
  float w = 0.f;
  if (k < K && co < CO) {
    int ci = k / (KS * KS), r = k % (KS * KS), dy = r / KS, dx = r % KS;
    w = Wc[((co * CIN + ci) * KS + dy) * KS + dx];
  }
  unsigned b0 = rne_bf16_bits(w);
  float f0 = __uint_as_float(b0 << 16);
  float d1 = w - f0;
  unsigned b1 = rne_bf16_bits(d1);
  float f1 = __uint_as_float(b1 << 16);
  unsigned b2 = rne_bf16_bits(d1 - f1);
  Wm[i] = (ushort)b0;
  Wm[PLANE + i] = (ushort)b1;
  Wm[2 * PLANE + i] = (ushort)b2;
}

// ---------------- conv_mfma_d: direct store, NSUB n-tiles per wave (L1) --------
// Per (co,j) a wave stores NSUB adjacent 64-B runs back-to-back -> L2 merges.
template <int CIN, int HW, int KS, int PAD, int CO, int RS, int NW, int NSUB>
__global__ __launch_bounds__(NW * 64) void conv_mfma_d(const float* __restrict__ S,
                                                       const ushort* __restrict__ Wm,
                                                       float* __restrict__ U) {
  constexpr int PH = HW + 2 * PAD;
  constexpr int K = CIN * KS * KS;
  constexpr int KC = (K + 31) / 32;
  constexpr int MT = (CO + 15) / 16;
  constexpr int N = HW * HW;
  constexpr int NT = (N + 15) / 16;
  constexpr int NG = (NT + NSUB - 1) / NSUB;
  constexpr int TILE = CIN * PH * RS;
  constexpr int KPAD = KC * 32;
  __shared__ float lin[TILE];
  __shared__ int koff[KPAD];
  const int t = blockIdx.x, b = blockIdx.y, B = gridDim.y;
  const int tid = threadIdx.x;

  for (int i = tid; i < TILE; i += NW * 64) lin[i] = 0.f;
  for (int k = tid; k < KPAD; k += NW * 64) {
    int ci = k / (KS * KS), r = k % (KS * KS), dy = r / KS, dx = r % KS;
    koff[k] = (k < K) ? (ci * PH * RS + dy * RS + dx) : 0;
  }
  __syncthreads();
  const float* src = S + ((long)t * B + b) * (CIN * N);
  for (int i = tid; i < CIN * N; i += NW * 64) {
    int ci = i / N, r = i % N, iy = r / HW, ix = r % HW;
    lin[ci * PH * RS + (iy + PAD) * RS + ix + PAD] = src[i];
  }
  __syncthreads();

  const int lane = tid & 63;
  const int wv = tid >> 6;
  const int g = lane >> 4;
  const int col = lane & 15;

  bf16x8 af[3 * MT * KC];  // L1: 12 frags (48 VGPR)
#pragma unroll
  for (int f = 0; f < 3 * MT * KC; ++f)
    af[f] = *(const bf16x8*)(Wm + (long)f * 512 + lane * 8);

  for (int grp = wv; grp < NG; grp += NW) {
    const int px0 = grp * (16 * NSUB);
    bool vs[NSUB];
    int pxb[NSUB];
    bf16x8 bf[NSUB][KC];
#pragma unroll
    for (int s = 0; s < NSUB; ++s) {
      int px = px0 + s * 16 + col;
      vs[s] = px < N;
      int ppx = vs[s] ? px : 0;
      int y = ppx / HW, x = ppx % HW;
      pxb[s] = y * RS + x;
#pragma unroll
      for (int kc = 0; kc < KC; ++kc) {
        bf16x8 v;
#pragma unroll
        for (int e = 0; e < 8; ++e) {
          float val = lin[pxb[s] + koff[kc * 32 + g * 8 + e]];
          v[e] = (short)(__float_as_uint(val) >> 16);  // exact for 0/1
        }
        bf[s][kc] = v;
      }
    }

#pragma unroll
    for (int m = 0; m < MT; ++m) {
      f32x4 acc[NSUB];
#pragma unroll
      for (int s = 0; s < NSUB; ++s) acc[s] = (f32x4){0.f, 0.f, 0.f, 0.f};
#pragma unroll
      for (int p = 0; p < 3; ++p) {
#pragma unroll
        for (int kc = 0; kc < KC; ++kc) {
          bf16x8 a = af[(p * MT + m) * KC + kc];
#pragma unroll
          for (int s = 0; s < NSUB; ++s)
            acc[s] = __builtin_amdgcn_mfma_f32_16x16x32_bf16(a, bf[s][kc], acc[s], 0, 0, 0);
        }
      }
      const int co0 = m * 16 + g * 4;  // D row = g*4 + reg (r20-r24 verified)
#pragma unroll
      for (int s = 0; s < NSUB; ++s) {
        if (vs[s]) {
          float* up = U + (((long)t * B + b) * CO + co0) * N + px0 + s * 16 + col;
#pragma unroll
          for (int j = 0; j < 4; ++j)
            if (co0 + j < CO) up[(long)j * N] = acc[s][j];
        }
      }
    }
  }
}

// ---------------- conv_mfma_b: kc-blocked A-in-regs + LDS C-staging (L3, L5) ---
// = r24's conv_mfma_s with af loaded in KCB-fragment blocks (28 VGPR) so the
// live set (af[KCB]+acc[CH]) stays < 128 VGPR -> NO SPILL.
// Per chunk (MCHUNK m-tiles): wave wv -> m_local = wv/WPM, slice = wv%WPM.
// acc[CH] across planes; C -> cst LDS -> float4 stream (full-line writes).
template <int CIN, int HW, int KS, int PAD, int CO, int RS, int NW, int MCHUNK, int KCB>
__global__ __launch_bounds__(NW * 64) void conv_mfma_b(const float* __restrict__ S,
                                                       const ushort* __restrict__ Wm,
                                                       float* __restrict__ U) {
  constexpr int PH = HW + 2 * PAD;
  constexpr int K = CIN * KS * KS;
  constexpr int KC = (K + 31) / 32;
  constexpr int MT = CO / 16;            // CO multiple of 16 (48, 96)
  constexpr int N = HW * HW;
  constexpr int NT = (N + 15) / 16;
  constexpr int TILE = CIN * PH * RS;
  constexpr int KPAD = KC * 32;
  constexpr int NCH = MT / MCHUNK;
  constexpr int WPM = NW / MCHUNK;
  constexpr int CH = (NT + WPM - 1) / WPM;
  constexpr int CROWS = MCHUNK * 16;
  constexpr int KB = KC / KCB;
  static_assert(KC % KCB == 0, "KCB must divide KC");
  __shared__ float lin[TILE];
  __shared__ int koff[KPAD];
  __shared__ float cst[CROWS * N];
  const int t = blockIdx.x, b = blockIdx.y, B = gridDim.y;
  const int tid = threadIdx.x;

  for (int i = tid; i < TILE; i += NW * 64) lin[i] = 0.f;
  for (int k = tid; k < KPAD; k += NW * 64) {
    int ci = k / (KS * KS), r = k % (KS * KS), dy = r / KS, dx = r % KS;
    koff[k] = (k < K) ? (ci * PH * RS + dy * RS + dx) : 0;
  }
  __syncthreads();
  const float* src = S + ((long)t * B + b) * (CIN * N);
  for (int i = tid; i < CIN * N; i += NW * 64) {
    int ci = i / N, r = i % N, iy = r / HW, ix = r % HW;
    lin[ci * PH * RS + (iy + PAD) * RS + ix + PAD] = src[i];
  }
  __syncthreads();

  const int lane = tid & 63;
  const int wv = tid >> 6;
  const int g = lane >> 4;
  const int col = lane & 15;
  const int m_local = wv / WPM;
  const int nt0 = (wv % WPM) * CH;

  bool vpx[CH];
  int pxb[CH];
#pragma unroll
  for (int i = 0; i < CH; ++i) {
    int px = (nt0 + i) * 16 + col;
    vpx[i] = px < N;
    int ppx = vpx[i] ? px : 0;
    int y = ppx / HW, x = ppx % HW;
    pxb[i] = y * RS + x;
  }

  for (int ch = 0; ch < NCH; ++ch) {
    const int m = ch * MCHUNK + m_local;
    f32x4 acc[CH];
#pragma unroll
    for (int i = 0; i < CH; ++i) acc[i] = (f32x4){0.f, 0.f, 0.f, 0.f};

#pragma unroll
    for (int p = 0; p < 3; ++p) {
#pragma unroll
      for (int kb = 0; kb < KB; ++kb) {
        bf16x8 af[KCB];  // 28 VGPR at KCB=7 -- the no-spill block size
#pragma unroll
        for (int q = 0; q < KCB; ++q)
          af[q] = *(const bf16x8*)(Wm + ((long)(p * MT + m) * KC + kb * KCB + q) * 512 + lane * 8);
#pragma unroll
        for (int i = 0; i < CH; ++i) {
          if ((nt0 + i) * 16 >= N) continue;  // wave-uniform skip
#pragma unroll
          for (int q = 0; q < KCB; ++q) {
            const int kc = kb * KCB + q;
            bf16x8 v;
#pragma unroll
            for (int e = 0; e < 8; ++e) {
              float val = lin[pxb[i] + koff[kc * 32 + g * 8 + e]];
              v[e] = (short)(__float_as_uint(val) >> 16);  // exact for 0/1
            }
            acc[i] = __builtin_amdgcn_mfma_f32_16x16x32_bf16(af[q], v, acc[i], 0, 0, 0);
          }
        }
      }
    }

    // write C chunk to LDS (D row = g*4 + reg, col = lane&15; r20-r24 verified)
    const int r0 = m_local * 16 + g * 4;
#pragma unroll
    for (int i = 0; i < CH; ++i) {
      if (vpx[i]) {
        const int px = (nt0 + i) * 16 + col;
#pragma unroll
        for (int j = 0; j < 4; ++j) cst[(r0 + j) * N + px] = acc[i][j];
      }
    }
    __syncthreads();
    // stream chunk (contiguous [CROWS][N] region of U) as float4
    const f32x4* cs = (const f32x4*)cst;
    f32x4* ug = (f32x4*)(U + (((long)t * B + b) * CO + ch * CROWS) * N);
    for (int i = tid; i < CROWS * N / 4; i += NW * 64) ug[i] = cs[i];
    __syncthreads();
  }
}

// ---------------- fused psp->pool(x11)->psp, 4 lanes/neuron, 4-deep prefetch ----------------
template <int C, int HIN, int HOUT>
__global__ __launch_bounds__(128) void ppp4_tm(const float* __restrict__ U,
                                               float* __restrict__ out, int B) {
  const int NOUT = B * C * HOUT * HOUT;
  const long SIN = (long)B * C * HIN * HIN;
  int id = blockIdx.x * 128 + threadIdx.x;
  int sub = id & 3, m = id >> 2;
  bool active = m < NOUT;
  int mm = active ? m : 0;
  int x2 = mm % HOUT;
  int y2 = (mm / HOUT) % HOUT;
  int c = (mm / (HOUT * HOUT)) % C;
  int b = mm / (C * HOUT * HOUT);
  int iy = 2 * y2 + (sub >> 1), ix = 2 * x2 + (sub & 1);
  bool valid = active && iy < HIN && ix < HIN;
  const float* base = U + ((long)(b * C + c) * HIN + iy) * HIN + ix;
  bool writer = active && (sub == 0);
  float* op = out + mm;
  IIR si, so;
  float pr0 = valid ? base[0] : 0.f;
  float pr1 = valid ? base[SIN] : 0.f;
  float pr2 = valid ? base[2 * SIN] : 0.f;
  float pr3 = valid ? base[3 * SIN] : 0.f;
  for (int tb = 0; tb < TT; tb += 4) {
    float a0 = pr0, a1 = pr1, a2 = pr2, a3 = pr3;
    const float* nb = base + (long)(tb + 4) * SIN;  // last iter overreads into ws
    pr0 = valid ? nb[0] : 0.f;
    pr1 = valid ? nb[SIN] : 0.f;
    pr2 = valid ? nb[2 * SIN] : 0.f;
    pr3 = valid ? nb[3 * SIN] : 0.f;
    {
      float s = si.step(a0);
      float v = s + __shfl_xor(s, 1); v += __shfl_xor(v, 2);
      float o = so.step(11.0f * v);
      if (writer) op[(long)tb * NOUT] = o;
    }
    {
      float s = si.step(a1);
      float v = s + __shfl_xor(s, 1); v += __shfl_xor(v, 2);
      float o = so.step(11.0f * v);
      if (writer) op[(long)(tb + 1) * NOUT] = o;
    }
    {
      float s = si.step(a2);
      float v = s + __shfl_xor(s, 1); v += __shfl_xor(v, 2);
      float o = so.step(11.0f * v);
      if (writer) op[(long)(tb + 2) * NOUT] = o;
    }
    {
      float s = si.step(a3);
      float v = s + __shfl_xor(s, 1); v += __shfl_xor(v, 2);
      float o = so.step(11.0f * v);
      if (writer) op[(long)(tb + 3) * NOUT] = o;
    }
  }
}

// ---------------- dense7k: split-k x8 GEMM, P[kz][row][o] partials ----------------
__global__ __launch_bounds__(256) void dense7k(const float* __restrict__ S,
                                               const float* __restrict__ Wt,
                                               float* __restrict__ P) {
  const int r0 = blockIdx.x * 16 + (threadIdx.x >> 6) * 4;
  const int kz = blockIdx.y;
  const int lane = threadIdx.x & 63;
  const float* s0 = S + (long)r0 * 2400;
  const float* s1 = s0 + 2400;
  const float* s2 = s0 + 4800;
  const float* s3 = s0 + 7200;
  const float* wp = Wt + lane * 4;
  v2f aA[4], aB[4];
#pragma unroll
  for (int o = 0; o < 4; ++o) { aA[o] = (v2f)(0.f); aB[o] = (v2f)(0.f); }
  const int k0 = kz * 300, k1 = k0 + 300;
  for (int k = k0; k < k1; k += 4) {
    float4 a0 = *(const float4*)(s0 + k);
    float4 a1 = *(const float4*)(s1 + k);
    float4 a2 = *(const float4*)(s2 + k);
    float4 a3 = *(const float4*)(s3 + k);
#define DSTEP(KK, AX)                                                        \
    {                                                                        \
      float4 w = *(const float4*)(wp + (long)(k + KK) * 256);                \
      v2f pA, pB;                                                            \
      pA.x = a0.AX; pA.y = a1.AX; pB.x = a2.AX; pB.y = a3.AX;                \
      aA[0] += pA * w.x; aA[1] += pA * w.y; aA[2] += pA * w.z; aA[3] += pA * w.w; \
      aB[0] += pB * w.x; aB[1] += pB * w.y; aB[2] += pB * w.z; aB[3] += pB * w.w; \
    }
    DSTEP(0, x) DSTEP(1, y) DSTEP(2, z) DSTEP(3, w)
#undef DSTEP
  }
  float* p = P + (long)kz * 307200 + (long)r0 * 256 + lane * 4;
#pragma unroll
  for (int o = 0; o < 4; ++o) p[o] = aA[o].x;
#pragma unroll
  for (int o = 0; o < 4; ++o) p[256 + o] = aA[o].y;
#pragma unroll
  for (int o = 0; o < 4; ++o) p[512 + o] = aB[o].x;
#pragma unroll
  for (int o = 0; o < 4; ++o) p[768 + o] = aB[o].y;
}

// ---------------- reduce8: U7 = sum of 8 partials (float4, ascending kz) ----------------
__global__ __launch_bounds__(256) void reduce8(const float* __restrict__ P,
                                               float* __restrict__ U7) {
  int i = blockIdx.x * 256 + threadIdx.x;  // over 76800 float4s
  if (i >= 76800) return;
  const float4* p = (const float4*)P;
  float4 a = p[i];
#pragma unroll
  for (int kz = 1; kz < 8; ++kz) {
    float4 b = p[(long)kz * 76800 + i];
    a.x += b.x; a.y += b.y; a.z += b.z; a.w += b.w;
  }
  ((float4*)U7)[i] = a;
}

// ---------------- psp7: psp+spike over U7, 4-deep prefetch ----------------
__global__ __launch_bounds__(128) void psp7(const float* __restrict__ U7,
                                            float* __restrict__ out) {
  int n = blockIdx.x * 128 + threadIdx.x;  // 0..1023
  IIR st;
  float pr0 = U7[n], pr1 = U7[1024 + n], pr2 = U7[2048 + n], pr3 = U7[3072 + n];
  for (int tb = 0; tb < TT; tb += 4) {
    float a0 = pr0, a1 = pr1, a2 = pr2, a3 = pr3;
    const float* nb = U7 + (long)(tb + 4) * 1024 + n;  // overreads into ws at end
    pr0 = nb[0]; pr1 = nb[1024]; pr2 = nb[2048]; pr3 = nb[3072];
    out[(long)tb * 1024 + n] = st.step(a0);
    out[(long)(tb + 1) * 1024 + n] = st.step(a1);
    out[(long)(tb + 2) * 1024 + n] = st.step(a2);
    out[(long)(tb + 3) * 1024 + n] = st.step(a3);
  }
}

// ---------------- dense8 ----------------
__global__ __launch_bounds__(256) void dense8(const float* __restrict__ S,
                                              const float* __restrict__ W,
                                              float* __restrict__ U) {
  int id = blockIdx.x * 256 + threadIdx.x;
  if (id >= 12000) return;
  int o = id % 10, row = id / 10;
  const float* sr = S + (long)row * 256;
  const float* wr = W + o * 256;
  float acc = 0.f;
  for (int k = 0; k < 256; k += 4) {
    float4 a = *(const float4*)(sr + k);
    float4 w = *(const float4*)(wr + k);
    acc += a.x * w.x; acc += a.y * w.y; acc += a.z * w.z; acc += a.w * w.w;
  }
  U[id] = acc;
}

// ---------------- final psp+spike + transpose to (B,10,T), prefetched ----------------
__global__ void psp8_out(const float* __restrict__ U, float* __restrict__ out) {
  int n = threadIdx.x;
  bool act = n < 40;
  int nn = act ? n : 0;
  IIR st;
  float pr0 = U[nn], pr1 = U[40 + nn], pr2 = U[80 + nn], pr3 = U[120 + nn];
  for (int tb = 0; tb < TT; tb += 4) {
    float a0 = pr0, a1 = pr1, a2 = pr2, a3 = pr3;
    const float* nb = U + (long)(tb + 4) * 40 + nn;  // overreads into ws at end
    pr0 = nb[0]; pr1 = nb[40]; pr2 = nb[80]; pr3 = nb[120];
    float o0 = st.step(a0), o1 = st.step(a1), o2 = st.step(a2), o3 = st.step(a3);
    if (act) {
      out[nn * TT + tb] = o0;
      out[nn * TT + tb + 1] = o1;
      out[nn * TT + tb + 2] = o2;
      out[nn * TT + tb + 3] = o3;
    }
  }
}

extern "C" void kernel_launch(void* const* d_in, const int* in_sizes, int n_in,
                              void* d_out, int out_size, void* d_ws, size_t ws_size,
                              hipStream_t stream) {
  const float* s_in = (const float*)d_in[0];
  const float* Wc1  = (const float*)d_in[1];
  const float* Wc2  = (const float*)d_in[2];
  const float* Wc3  = (const float*)d_in[3];
  const float* Wd4a = (const float*)d_in[4];
  const float* Wd4b = (const float*)d_in[5];

  float* Buf1 = (float*)d_ws;            // 33,292,800 floats (U1/U3/U5)
  float* Buf2 = Buf1 + 33292800;
  float* s2   = Buf2;                    //  8,323,200
  float* s4   = Buf2 + 8323200;          //  4,665,600
  float* Wt4a = Buf2 + 12988800;         //    614,400
  float* T0   = Buf2 + 13910400;         //  2,774,400
  float* s7   = Buf2 + 16737840;         //    307,200
  float* P7   = Buf2 + 17045040;         //  2,457,600 (8 x 307,200 partials)
  float* U7   = Buf2 + 19502640;         //    307,200
  float* s6   = Buf2;                    //  2,880,000 (s2 region, dead by L6)
  float* U8   = Buf1;                    //     12,000 (Buf1 dead by L8)
  // MFMA weight planes live in P7's region (first written by dense7k, which
  // runs after every conv has finished reading Wm -- stream-ordered).
  ushort* Wm1 = (ushort*)P7;             //  18,432 ushorts (3 x 2m x 2kc x 512)
  ushort* Wm2 = Wm1 + 18432;             //  32,256 ushorts (3 x 3m x 7kc x 512)
  ushort* Wm3 = Wm1 + 50688;             // 129,024 ushorts (3 x 6m x 14kc x 512)

  // prep: input -> time-major; Wd4a -> [k][o]; conv weights -> MFMA planes
  transpose_rc<<<dim3(5, 145), 256, 0, stream>>>(s_in, T0, 9248, 300);
  transpose_rc<<<dim3(38, 4), 256, 0, stream>>>(Wd4a, Wt4a, 256, 2400);
  prep_mfma<2, 5, 24, 2, 2><<<24, 256, 0, stream>>>(Wc1, Wm1);
  prep_mfma<24, 3, 48, 3, 7><<<42, 256, 0, stream>>>(Wc2, Wm2);
  prep_mfma<48, 3, 96, 6, 14><<<168, 256, 0, stream>>>(Wc3, Wm3);

  // L1: conv 2->24 k5 p2, MFMA direct store (NSUB=4 -> 256-B runs per co)
  conv_mfma_d<2, 34, 5, 2, 24, 39, 8, 4><<<dim3(300, 4), 512, 0, stream>>>(T0, Wm1, Buf1);
  // L1-psp + pool 34->17 + psp -> s2
  ppp4_tm<24, 34, 17><<<867, 128, 0, stream>>>(Buf1, s2, 4);
  // L3: conv 24->48 k3 p1, MFMA kc-blocked (8 waves share m-tile; 3 chunks)
  conv_mfma_b<24, 17, 3, 1, 48, 19, 8, 1, 7><<<dim3(300, 4), 512, 0, stream>>>(s2, Wm2, Buf1);
  // L3-psp + pool 17->9 + psp -> s4
  ppp4_tm<48, 17, 9><<<486, 128, 0, stream>>>(Buf1, s4, 4);
  // L5: conv 48->96 k3 p1, MFMA kc-blocked (6 waves = 6 m-tiles; KCB=7 x 2)
  conv_mfma_b<48, 9, 3, 1, 96, 13, 6, 6, 7><<<dim3(300, 4), 384, 0, stream>>>(s4, Wm3, Buf1);
  // L5-psp + pool 9->5 + psp -> s6
  ppp4_tm<96, 9, 5><<<300, 128, 0, stream>>>(Buf1, s6, 4);
  // L7: dense 2400->256 split-k x8 ; fold partials ; psp -> s7
  dense7k<<<dim3(75, 8), 256, 0, stream>>>(s6, Wt4a, P7);
  reduce8<<<300, 256, 0, stream>>>(P7, U7);
  psp7<<<8, 128, 0, stream>>>(U7, s7);
  // L8: dense 256->10 ; psp + output transpose
  dense8<<<47, 256, 0, stream>>>(s7, Wd4b, U8);
  psp8_out<<<1, 64, 0, stream>>>(U8, (float*)d_out);
}

// Round 12
// 601.961 us; speedup vs baseline: 1.3163x; 1.3163x over previous
//
#include <hip/hip_runtime.h>

// SLAYER SNN forward, round 27 = round 26 resubmitted verbatim (round-26
// bench died on container acquisition; static audit found no hang/OOB/
// alignment/capture hazards -- same flake as round 19/20, which passed on
// verbatim resubmission).
// round 26 = round 22 (best measured, 592.7us) with ONE change: L5's
// m-chunks split across gridDim.z (z=2, MCHUNK=3) -> 2400 smaller blocks,
// LDS 60.4->44.8KB, better balance/tail. Code path, VGPR (88, no spill),
// and per-output accumulation order (p{kc}) identical.
// POST-MORTEM r23-r25: all three wave-owns-m variants spilled (VGPR pinned
// 128, WRITE 300-488MB = scratch) because the scheduler hoists the 8-scalar-
// read B-gathers across unrolled bodies; and even spill-free, rebuilding bf
// per plane/m has a ~47us B-gather floor. bf[14]-resident (wave-owns-nt,
// r22's conv_mfma_c) is the right family; its costs are A-loads from L2
// (~52us) and 12-wave residency -- addressed incrementally from here.
// All fp32 elsewhere; IIR op ordering bit-matches the reference scan.

#define TT 300

#define A1 0.9048374180359595f   // exp(-1/10)
#define C1 0.2718281828459045f   // e/10
#define A2 0.36787944117144233f  // exp(-1)
#define C2 2.718281828459045f    // e
#define KREF (20.0f * C2)
#define THETA_F 10.0f

typedef float v2f __attribute__((ext_vector_type(2)));
typedef float f32x4 __attribute__((ext_vector_type(4)));
typedef short bf16x8 __attribute__((ext_vector_type(8)));

struct IIR {
  float p1, q1, p2, q2;
  __device__ IIR() : p1(0.f), q1(0.f), p2(0.f), q2(0.f) {}
  __device__ inline float step(float xin) {
    q1 = A1 * q1 + A1 * p1;
    float y = C1 * q1;
    p1 = A1 * p1 + xin;
    q2 = A2 * q2 + A2 * p2;
    float u = y - KREF * q2;
    float s = (u >= THETA_F) ? 1.0f : 0.0f;
    p2 = A2 * p2 + s;
    return s;
  }
};

// ---------------- generic tiled transpose: in[R][C] -> out[C][R] ----------------
__global__ __launch_bounds__(256) void transpose_rc(const float* __restrict__ in,
                                                    float* __restrict__ out,
                                                    int R, int C) {
  __shared__ float tile[64][65];
  int c0 = blockIdx.x * 64, r0 = blockIdx.y * 64;
  int tx = threadIdx.x & 63, ty = threadIdx.x >> 6;
  for (int i = ty; i < 64; i += 4) {
    int r = r0 + i, c = c0 + tx;
    if (r < R && c < C) tile[i][tx] = in[(long)r * C + c];
  }
  __syncthreads();
  for (int i = ty; i < 64; i += 4) {
    int c = c0 + i, r = r0 + tx;
    if (c < C && r < R) out[(long)c * R + r] = tile[tx][i];
  }
}

// ---------------- prep_mfma: 3-plane exact bf16 split, fragment-major ----------
// Wm[p][m][kc][lane][e] ushort; co = m*16 + (lane&15); k = kc*32+(lane>>4)*8+e;
// k>=K or co>=CO -> exact 0 in all planes (lets conv skip B-side guards).
__device__ inline unsigned rne_bf16_bits(float f) {
  unsigned u = __float_as_uint(f);
  return (u + 0x7FFFu + ((u >> 16) & 1u)) >> 16;
}
template <int CIN, int KS, int CO, int MT, int KC>
__global__ __launch_bounds__(256) void prep_mfma(const float* __restrict__ Wc,
                                                 ushort* __restrict__ Wm) {
  constexpr int K = CIN * KS * KS;
  constexpr int PLANE = MT * KC * 512;
  int i = blockIdx.x * 256 + threadIdx.x;
  if (i >= PLANE) return;
  int e = i & 7, l = (i >> 3) & 63;
  int rest = i >> 9;
  int kc = rest % KC, m = rest / KC;
  int co = m * 16 + (l & 15);
  int k = kc * 32 + (l >> 4) * 8 + e;
  float w = 0.f;
  if (k < K && co < CO) {
    int ci = k / (KS * KS), r = k % (KS * KS), dy = r / KS, dx = r % KS;
    w = Wc[((co * CIN + ci) * KS + dy) * KS + dx];
  }
  unsigned b0 = rne_bf16_bits(w);
  float f0 = __uint_as_float(b0 << 16);
  float d1 = w - f0;
  unsigned b1 = rne_bf16_bits(d1);
  float f1 = __uint_as_float(b1 << 16);
  unsigned b2 = rne_bf16_bits(d1 - f1);
  Wm[i] = (ushort)b0;
  Wm[PLANE + i] = (ushort)b1;
  Wm[2 * PLANE + i] = (ushort)b2;
}

// ---------------- conv_mfma_d: direct store, NSUB n-tiles per wave (L1) --------
// Per (co,j) a wave stores NSUB adjacent 64-B runs back-to-back -> L2 merges.
template <int CIN, int HW, int KS, int PAD, int CO, int RS, int NW, int NSUB>
__global__ __launch_bounds__(NW * 64) void conv_mfma_d(const float* __restrict__ S,
                                                       const ushort* __restrict__ Wm,
                                                       float* __restrict__ U) {
  constexpr int PH = HW + 2 * PAD;
  constexpr int K = CIN * KS * KS;
  constexpr int KC = (K + 31) / 32;
  constexpr int MT = (CO + 15) / 16;
  constexpr int N = HW * HW;
  constexpr int NT = (N + 15) / 16;
  constexpr int NG = (NT + NSUB - 1) / NSUB;
  constexpr int TILE = CIN * PH * RS;
  constexpr int KPAD = KC * 32;
  __shared__ float lin[TILE];
  __shared__ int koff[KPAD];
  const int t = blockIdx.x, b = blockIdx.y, B = gridDim.y;
  const int tid = threadIdx.x;

  for (int i = tid; i < TILE; i += NW * 64) lin[i] = 0.f;
  for (int k = tid; k < KPAD; k += NW * 64) {
    int ci = k / (KS * KS), r = k % (KS * KS), dy = r / KS, dx = r % KS;
    koff[k] = (k < K) ? (ci * PH * RS + dy * RS + dx) : 0;
  }
  __syncthreads();
  const float* src = S + ((long)t * B + b) * (CIN * N);
  for (int i = tid; i < CIN * N; i += NW * 64) {
    int ci = i / N, r = i % N, iy = r / HW, ix = r % HW;
    lin[ci * PH * RS + (iy + PAD) * RS + ix + PAD] = src[i];
  }
  __syncthreads();

  const int lane = tid & 63;
  const int wv = tid >> 6;
  const int g = lane >> 4;
  const int col = lane & 15;

  bf16x8 af[3 * MT * KC];  // L1: 12 frags (48 VGPR)
#pragma unroll
  for (int f = 0; f < 3 * MT * KC; ++f)
    af[f] = *(const bf16x8*)(Wm + (long)f * 512 + lane * 8);

  for (int grp = wv; grp < NG; grp += NW) {
    const int px0 = grp * (16 * NSUB);
    bool vs[NSUB];
    int pxb[NSUB];
    bf16x8 bf[NSUB][KC];
#pragma unroll
    for (int s = 0; s < NSUB; ++s) {
      int px = px0 + s * 16 + col;
      vs[s] = px < N;
      int ppx = vs[s] ? px : 0;
      int y = ppx / HW, x = ppx % HW;
      pxb[s] = y * RS + x;
#pragma unroll
      for (int kc = 0; kc < KC; ++kc) {
        bf16x8 v;
#pragma unroll
        for (int e = 0; e < 8; ++e) {
          float val = lin[pxb[s] + koff[kc * 32 + g * 8 + e]];
          v[e] = (short)(__float_as_uint(val) >> 16);  // exact for 0/1
        }
        bf[s][kc] = v;
      }
    }

#pragma unroll
    for (int m = 0; m < MT; ++m) {
      f32x4 acc[NSUB];
#pragma unroll
      for (int s = 0; s < NSUB; ++s) acc[s] = (f32x4){0.f, 0.f, 0.f, 0.f};
#pragma unroll
      for (int p = 0; p < 3; ++p) {
#pragma unroll
        for (int kc = 0; kc < KC; ++kc) {
          bf16x8 a = af[(p * MT + m) * KC + kc];
#pragma unroll
          for (int s = 0; s < NSUB; ++s)
            acc[s] = __builtin_amdgcn_mfma_f32_16x16x32_bf16(a, bf[s][kc], acc[s], 0, 0, 0);
        }
      }
      const int co0 = m * 16 + g * 4;  // D row = g*4 + reg (r20-r25 verified)
#pragma unroll
      for (int s = 0; s < NSUB; ++s) {
        if (vs[s]) {
          float* up = U + (((long)t * B + b) * CO + co0) * N + px0 + s * 16 + col;
#pragma unroll
          for (int j = 0; j < 4; ++j)
            if (co0 + j < CO) up[(long)j * N] = acc[s][j];
        }
      }
    }
  }
}

// ---------------- conv_mfma_c: C staged in LDS, streamed out (L3, L5) ----------
// Per chunk (MCHUNK m-tiles): waves accumulate into cst[MCHUNK*16][N], barrier,
// whole block streams the contiguous chunk to U as float4 -> full-line writes.
// Chunks distributed across gridDim.z (L5: z=2, one chunk each; L3: z=1, loop).
template <int CIN, int HW, int KS, int PAD, int CO, int RS, int NW, int MCHUNK>
__global__ __launch_bounds__(NW * 64) void conv_mfma_c(const float* __restrict__ S,
                                                       const ushort* __restrict__ Wm,
                                                       float* __restrict__ U) {
  constexpr int PH = HW + 2 * PAD;
  constexpr int K = CIN * KS * KS;
  constexpr int KC = (K + 31) / 32;
  constexpr int MT = CO / 16;            // CO multiple of 16 (48, 96)
  constexpr int N = HW * HW;
  constexpr int NT = (N + 15) / 16;
  constexpr int TILE = CIN * PH * RS;
  constexpr int KPAD = KC * 32;
  constexpr int NCH = MT / MCHUNK;       // CO multiple of 16*MCHUNK here
  constexpr int CROWS = MCHUNK * 16;
  __shared__ float lin[TILE];
  __shared__ int koff[KPAD];
  __shared__ float cst[CROWS * N];
  const int t = blockIdx.x, b = blockIdx.y, B = gridDim.y;
  const int tid = threadIdx.x;

  for (int i = tid; i < TILE; i += NW * 64) lin[i] = 0.f;
  for (int k = tid; k < KPAD; k += NW * 64) {
    int ci = k / (KS * KS), r = k % (KS * KS), dy = r / KS, dx = r % KS;
    koff[k] = (k < K) ? (ci * PH * RS + dy * RS + dx) : 0;
  }
  __syncthreads();
  const float* src = S + ((long)t * B + b) * (CIN * N);
  for (int i = tid; i < CIN * N; i += NW * 64) {
    int ci = i / N, r = i % N, iy = r / HW, ix = r % HW;
    lin[ci * PH * RS + (iy + PAD) * RS + ix + PAD] = src[i];
  }
  __syncthreads();

  const int lane = tid & 63;
  const int wv = tid >> 6;
  const int g = lane >> 4;
  const int col = lane & 15;

  for (int ch = blockIdx.z; ch < NCH; ch += gridDim.z) {
    for (int nt = wv; nt < NT; nt += NW) {
      int px = nt * 16 + col;
      bool vpx = px < N;
      int ppx = vpx ? px : 0;
      int y = ppx / HW, x = ppx % HW;
      const int pxbase = y * RS + x;

      bf16x8 bf[KC];
#pragma unroll
      for (int kc = 0; kc < KC; ++kc) {
        bf16x8 v;
#pragma unroll
        for (int e = 0; e < 8; ++e) {
          float val = lin[pxbase + koff[kc * 32 + g * 8 + e]];
          v[e] = (short)(__float_as_uint(val) >> 16);  // exact for 0/1
        }
        bf[kc] = v;
      }

#pragma unroll
      for (int ml = 0; ml < MCHUNK; ++ml) {
        const int m = ch * MCHUNK + ml;
        f32x4 acc = {0.f, 0.f, 0.f, 0.f};
#pragma unroll
        for (int p = 0; p < 3; ++p) {
#pragma unroll
          for (int kc = 0; kc < KC; ++kc) {
            bf16x8 a = *(const bf16x8*)(Wm + ((long)(p * MT + m) * KC + kc) * 512 + lane * 8);
            acc = __builtin_amdgcn_mfma_f32_16x16x32_bf16(a, bf[kc], acc, 0, 0, 0);
          }
        }
        if (vpx) {
          const int r0 = ml * 16 + g * 4;
#pragma unroll
          for (int j = 0; j < 4; ++j) cst[(r0 + j) * N + px] = acc[j];
        }
      }
    }
    __syncthreads();
    // stream chunk (contiguous [CROWS][N] region of U) as float4
    const f32x4* cs = (const f32x4*)cst;
    f32x4* ug = (f32x4*)(U + (((long)t * B + b) * CO + ch * CROWS) * N);
    for (int i = tid; i < CROWS * N / 4; i += NW * 64) ug[i] = cs[i];
    __syncthreads();
  }
}

// ---------------- fused psp->pool(x11)->psp, 4 lanes/neuron, 4-deep prefetch ----------------
template <int C, int HIN, int HOUT>
__global__ __launch_bounds__(128) void ppp4_tm(const float* __restrict__ U,
                                               float* __restrict__ out, int B) {
  const int NOUT = B * C * HOUT * HOUT;
  const long SIN = (long)B * C * HIN * HIN;
  int id = blockIdx.x * 128 + threadIdx.x;
  int sub = id & 3, m = id >> 2;
  bool active = m < NOUT;
  int mm = active ? m : 0;
  int x2 = mm % HOUT;
  int y2 = (mm / HOUT) % HOUT;
  int c = (mm / (HOUT * HOUT)) % C;
  int b = mm / (C * HOUT * HOUT);
  int iy = 2 * y2 + (sub >> 1), ix = 2 * x2 + (sub & 1);
  bool valid = active && iy < HIN && ix < HIN;
  const float* base = U + ((long)(b * C + c) * HIN + iy) * HIN + ix;
  bool writer = active && (sub == 0);
  float* op = out + mm;
  IIR si, so;
  float pr0 = valid ? base[0] : 0.f;
  float pr1 = valid ? base[SIN] : 0.f;
  float pr2 = valid ? base[2 * SIN] : 0.f;
  float pr3 = valid ? base[3 * SIN] : 0.f;
  for (int tb = 0; tb < TT; tb += 4) {
    float a0 = pr0, a1 = pr1, a2 = pr2, a3 = pr3;
    const float* nb = base + (long)(tb + 4) * SIN;  // last iter overreads into ws
    pr0 = valid ? nb[0] : 0.f;
    pr1 = valid ? nb[SIN] : 0.f;
    pr2 = valid ? nb[2 * SIN] : 0.f;
    pr3 = valid ? nb[3 * SIN] : 0.f;
    {
      float s = si.step(a0);
      float v = s + __shfl_xor(s, 1); v += __shfl_xor(v, 2);
      float o = so.step(11.0f * v);
      if (writer) op[(long)tb * NOUT] = o;
    }
    {
      float s = si.step(a1);
      float v = s + __shfl_xor(s, 1); v += __shfl_xor(v, 2);
      float o = so.step(11.0f * v);
      if (writer) op[(long)(tb + 1) * NOUT] = o;
    }
    {
      float s = si.step(a2);
      float v = s + __shfl_xor(s, 1); v += __shfl_xor(v, 2);
      float o = so.step(11.0f * v);
      if (writer) op[(long)(tb + 2) * NOUT] = o;
    }
    {
      float s = si.step(a3);
      float v = s + __shfl_xor(s, 1); v += __shfl_xor(v, 2);
      float o = so.step(11.0f * v);
      if (writer) op[(long)(tb + 3) * NOUT] = o;
    }
  }
}

// ---------------- dense7k: split-k x8 GEMM, P[kz][row][o] partials ----------------
__global__ __launch_bounds__(256) void dense7k(const float* __restrict__ S,
                                               const float* __restrict__ Wt,
                                               float* __restrict__ P) {
  const int r0 = blockIdx.x * 16 + (threadIdx.x >> 6) * 4;
  const int kz = blockIdx.y;
  const int lane = threadIdx.x & 63;
  const float* s0 = S + (long)r0 * 2400;
  const float* s1 = s0 + 2400;
  const float* s2 = s0 + 4800;
  const float* s3 = s0 + 7200;
  const float* wp = Wt + lane * 4;
  v2f aA[4], aB[4];
#pragma unroll
  for (int o = 0; o < 4; ++o) { aA[o] = (v2f)(0.f); aB[o] = (v2f)(0.f); }
  const int k0 = kz * 300, k1 = k0 + 300;
  for (int k = k0; k < k1; k += 4) {
    float4 a0 = *(const float4*)(s0 + k);
    float4 a1 = *(const float4*)(s1 + k);
    float4 a2 = *(const float4*)(s2 + k);
    float4 a3 = *(const float4*)(s3 + k);
#define DSTEP(KK, AX)                                                        \
    {                                                                        \
      float4 w = *(const float4*)(wp + (long)(k + KK) * 256);                \
      v2f pA, pB;                                                            \
      pA.x = a0.AX; pA.y = a1.AX; pB.x = a2.AX; pB.y = a3.AX;                \
      aA[0] += pA * w.x; aA[1] += pA * w.y; aA[2] += pA * w.z; aA[3] += pA * w.w; \
      aB[0] += pB * w.x; aB[1] += pB * w.y; aB[2] += pB * w.z; aB[3] += pB * w.w; \
    }
    DSTEP(0, x) DSTEP(1, y) DSTEP(2, z) DSTEP(3, w)
#undef DSTEP
  }
  float* p = P + (long)kz * 307200 + (long)r0 * 256 + lane * 4;
#pragma unroll
  for (int o = 0; o < 4; ++o) p[o] = aA[o].x;
#pragma unroll
  for (int o = 0; o < 4; ++o) p[256 + o] = aA[o].y;
#pragma unroll
  for (int o = 0; o < 4; ++o) p[512 + o] = aB[o].x;
#pragma unroll
  for (int o = 0; o < 4; ++o) p[768 + o] = aB[o].y;
}

// ---------------- reduce8: U7 = sum of 8 partials (float4, ascending kz) ----------------
__global__ __launch_bounds__(256) void reduce8(const float* __restrict__ P,
                                               float* __restrict__ U7) {
  int i = blockIdx.x * 256 + threadIdx.x;  // over 76800 float4s
  if (i >= 76800) return;
  const float4* p = (const float4*)P;
  float4 a = p[i];
#pragma unroll
  for (int kz = 1; kz < 8; ++kz) {
    float4 b = p[(long)kz * 76800 + i];
    a.x += b.x; a.y += b.y; a.z += b.z; a.w += b.w;
  }
  ((float4*)U7)[i] = a;
}

// ---------------- psp7: psp+spike over U7, 4-deep prefetch ----------------
__global__ __launch_bounds__(128) void psp7(const float* __restrict__ U7,
                                            float* __restrict__ out) {
  int n = blockIdx.x * 128 + threadIdx.x;  // 0..1023
  IIR st;
  float pr0 = U7[n], pr1 = U7[1024 + n], pr2 = U7[2048 + n], pr3 = U7[3072 + n];
  for (int tb = 0; tb < TT; tb += 4) {
    float a0 = pr0, a1 = pr1, a2 = pr2, a3 = pr3;
    const float* nb = U7 + (long)(tb + 4) * 1024 + n;  // overreads into ws at end
    pr0 = nb[0]; pr1 = nb[1024]; pr2 = nb[2048]; pr3 = nb[3072];
    out[(long)tb * 1024 + n] = st.step(a0);
    out[(long)(tb + 1) * 1024 + n] = st.step(a1);
    out[(long)(tb + 2) * 1024 + n] = st.step(a2);
    out[(long)(tb + 3) * 1024 + n] = st.step(a3);
  }
}

// ---------------- dense8 ----------------
__global__ __launch_bounds__(256) void dense8(const float* __restrict__ S,
                                              const float* __restrict__ W,
                                              float* __restrict__ U) {
  int id = blockIdx.x * 256 + threadIdx.x;
  if (id >= 12000) return;
  int o = id % 10, row = id / 10;
  const float* sr = S + (long)row * 256;
  const float* wr = W + o * 256;
  float acc = 0.f;
  for (int k = 0; k < 256; k += 4) {
    float4 a = *(const float4*)(sr + k);
    float4 w = *(const float4*)(wr + k);
    acc += a.x * w.x; acc += a.y * w.y; acc += a.z * w.z; acc += a.w * w.w;
  }
  U[id] = acc;
}

// ---------------- final psp+spike + transpose to (B,10,T), prefetched ----------------
__global__ void psp8_out(const float* __restrict__ U, float* __restrict__ out) {
  int n = threadIdx.x;
  bool act = n < 40;
  int nn = act ? n : 0;
  IIR st;
  float pr0 = U[nn], pr1 = U[40 + nn], pr2 = U[80 + nn], pr3 = U[120 + nn];
  for (int tb = 0; tb < TT; tb += 4) {
    float a0 = pr0, a1 = pr1, a2 = pr2, a3 = pr3;
    const float* nb = U + (long)(tb + 4) * 40 + nn;  // overreads into ws at end
    pr0 = nb[0]; pr1 = nb[40]; pr2 = nb[80]; pr3 = nb[120];
    float o0 = st.step(a0), o1 = st.step(a1), o2 = st.step(a2), o3 = st.step(a3);
    if (act) {
      out[nn * TT + tb] = o0;
      out[nn * TT + tb + 1] = o1;
      out[nn * TT + tb + 2] = o2;
      out[nn * TT + tb + 3] = o3;
    }
  }
}

extern "C" void kernel_launch(void* const* d_in, const int* in_sizes, int n_in,
                              void* d_out, int out_size, void* d_ws, size_t ws_size,
                              hipStream_t stream) {
  const float* s_in = (const float*)d_in[0];
  const float* Wc1  = (const float*)d_in[1];
  const float* Wc2  = (const float*)d_in[2];
  const float* Wc3  = (const float*)d_in[3];
  const float* Wd4a = (const float*)d_in[4];
  const float* Wd4b = (const float*)d_in[5];

  float* Buf1 = (float*)d_ws;            // 33,292,800 floats (U1/U3/U5)
  float* Buf2 = Buf1 + 33292800;
  float* s2   = Buf2;                    //  8,323,200
  float* s4   = Buf2 + 8323200;          //  4,665,600
  float* Wt4a = Buf2 + 12988800;         //    614,400
  float* T0   = Buf2 + 13910400;         //  2,774,400
  float* s7   = Buf2 + 16737840;         //    307,200
  float* P7   = Buf2 + 17045040;         //  2,457,600 (8 x 307,200 partials)
  float* U7   = Buf2 + 19502640;         //    307,200
  float* s6   = Buf2;                    //  2,880,000 (s2 region, dead by L6)
  float* U8   = Buf1;                    //     12,000 (Buf1 dead by L8)
  // MFMA weight planes live in P7's region (first written by dense7k, which
  // runs after every conv has finished reading Wm -- stream-ordered).
  ushort* Wm1 = (ushort*)P7;             //  18,432 ushorts (3 x 2m x 2kc x 512)
  ushort* Wm2 = Wm1 + 18432;             //  32,256 ushorts (3 x 3m x 7kc x 512)
  ushort* Wm3 = Wm1 + 50688;             // 129,024 ushorts (3 x 6m x 14kc x 512)

  // prep: input -> time-major; Wd4a -> [k][o]; conv weights -> MFMA planes
  transpose_rc<<<dim3(5, 145), 256, 0, stream>>>(s_in, T0, 9248, 300);
  transpose_rc<<<dim3(38, 4), 256, 0, stream>>>(Wd4a, Wt4a, 256, 2400);
  prep_mfma<2, 5, 24, 2, 2><<<24, 256, 0, stream>>>(Wc1, Wm1);
  prep_mfma<24, 3, 48, 3, 7><<<42, 256, 0, stream>>>(Wc2, Wm2);
  prep_mfma<48, 3, 96, 6, 14><<<168, 256, 0, stream>>>(Wc3, Wm3);

  // L1: conv 2->24 k5 p2, MFMA direct store (NSUB=4 -> 256-B runs per co)
  conv_mfma_d<2, 34, 5, 2, 24, 39, 8, 4><<<dim3(300, 4), 512, 0, stream>>>(T0, Wm1, Buf1);
  // L1-psp + pool 34->17 + psp -> s2
  ppp4_tm<24, 34, 17><<<867, 128, 0, stream>>>(Buf1, s2, 4);
  // L3: conv 24->48 k3 p1, MFMA C-staged (3 chunks of 16 co; 54KB LDS)
  conv_mfma_c<24, 17, 3, 1, 48, 19, 8, 1><<<dim3(300, 4), 512, 0, stream>>>(s2, Wm2, Buf1);
  // L3-psp + pool 17->9 + psp -> s4
  ppp4_tm<48, 17, 9><<<486, 128, 0, stream>>>(Buf1, s4, 4);
  // L5: conv 48->96 k3 p1, MFMA C-staged, z-split (2 chunks of 48 co; 44.8KB)
  conv_mfma_c<48, 9, 3, 1, 96, 13, 6, 3><<<dim3(300, 4, 2), 384, 0, stream>>>(s4, Wm3, Buf1);
  // L5-psp + pool 9->5 + psp -> s6
  ppp4_tm<96, 9, 5><<<300, 128, 0, stream>>>(Buf1, s6, 4);
  // L7: dense 2400->256 split-k x8 ; fold partials ; psp -> s7
  dense7k<<<dim3(75, 8), 256, 0, stream>>>(s6, Wt4a, P7);
  reduce8<<<300, 256, 0, stream>>>(P7, U7);
  psp7<<<8, 128, 0, stream>>>(U7, s7);
  // L8: dense 256->10 ; psp + output transpose
  dense8<<<47, 256, 0, stream>>>(s7, Wd4b, U8);
  psp8_out<<<1, 64, 0, stream>>>(U8, (float*)d_out);
}

// Round 13
// 553.883 us; speedup vs baseline: 1.4306x; 1.0868x over previous
//
#include <hip/hip_runtime.h>

// SLAYER SNN forward, round 28 = round 27 with the conv B-side vectorized.
// r27 cycle model: L5 = 24K cyc/block, of which ~23K is the B-gather (112
// scalar ds_read_u16 + cvt per bf[14] rebuild) -> L3/L5 are LDS-scalar-
// gather bound, NOT scheduling-bound.
//  - NEW k-bijection for L3/L5 (k = (dy*KS+dx)*CIN + ci, channel fastest),
//    applied identically to A (prep_mfma<...,CL=1>) and B, so it is a
//    within-MFMA k-slot reorder only (same numeric class as r20-r27, all
//    absmax 0).
//  - conv_mfma_v (L3,L5): input tile staged CHANNEL-LAST bf16 in LDS
//    (exact for 0/1 spikes); each B fragment = ONE ds_read_b128 (16
//    contiguous bytes = 8 consecutive ci). Per-pixel stride CPAD padded so
//    bank aliasing is 2-way (free): L5 CPAD=56, L3 CPAD=24. k>=K overreads
//    land in zero-filled extra rows (PHA = HW+3), A=0 there anyway.
//    LDS: L5 30.6KB, L3 37KB. Structure/store path otherwise = r27's
//    conv_mfma_c (wave-owns-nt, bf[KC] resident, cst LDS staging + float4
//    stream, L5 z-split).
//  - conv_mfma_d (L1) and everything downstream unchanged.
// All fp32 elsewhere; IIR op ordering bit-matches the reference scan.

#define TT 300

#define A1 0.9048374180359595f   // exp(-1/10)
#define C1 0.2718281828459045f   // e/10
#define A2 0.36787944117144233f  // exp(-1)
#define C2 2.718281828459045f    // e
#define KREF (20.0f * C2)
#define THETA_F 10.0f

typedef float v2f __attribute__((ext_vector_type(2)));
typedef float f32x4 __attribute__((ext_vector_type(4)));
typedef short bf16x8 __attribute__((ext_vector_type(8)));

struct IIR {
  float p1, q1, p2, q2;
  __device__ IIR() : p1(0.f), q1(0.f), p2(0.f), q2(0.f) {}
  __device__ inline float step(float xin) {
    q1 = A1 * q1 + A1 * p1;
    float y = C1 * q1;
    p1 = A1 * p1 + xin;
    q2 = A2 * q2 + A2 * p2;
    float u = y - KREF * q2;
    float s = (u >= THETA_F) ? 1.0f : 0.0f;
    p2 = A2 * p2 + s;
    return s;
  }
};

// ---------------- generic tiled transpose: in[R][C] -> out[C][R] ----------------
__global__ __launch_bounds__(256) void transpose_rc(const float* __restrict__ in,
                                                    float* __restrict__ out,
                                                    int R, int C) {
  __shared__ float tile[64][65];
  int c0 = blockIdx.x * 64, r0 = blockIdx.y * 64;
  int tx = threadIdx.x & 63, ty = threadIdx.x >> 6;
  for (int i = ty; i < 64; i += 4) {
    int r = r0 + i, c = c0 + tx;
    if (r < R && c < C) tile[i][tx] = in[(long)r * C + c];
  }
  __syncthreads();
  for (int i = ty; i < 64; i += 4) {
    int c = c0 + i, r = r0 + tx;
    if (c < C && r < R) out[(long)c * R + r] = tile[tx][i];
  }
}

// ---------------- prep_mfma: 3-plane exact bf16 split, fragment-major ----------
// Wm[p][m][kc][lane][e] ushort; co = m*16 + (lane&15); k = kc*32+(lane>>4)*8+e.
// CL=0: k = ci*KS*KS + dy*KS + dx (legacy, L1).
// CL=1: k = (dy*KS+dx)*CIN + ci (channel fastest -> contiguous B reads).
// k>=K or co>=CO -> exact 0 in all planes.
__device__ inline unsigned rne_bf16_bits(float f) {
  unsigned u = __float_as_uint(f);
  return (u + 0x7FFFu + ((u >> 16) & 1u)) >> 16;
}
template <int CIN, int KS, int CO, int MT, int KC, int CL>
__global__ __launch_bounds__(256) void prep_mfma(const float* __restrict__ Wc,
                                                 ushort* __restrict__ Wm) {
  constexpr int K = CIN * KS * KS;
  constexpr int PLANE = MT * KC * 512;
  int i = blockIdx.x * 256 + threadIdx.x;
  if (i >= PLANE) return;
  int e = i & 7, l = (i >> 3) & 63;
  int rest = i >> 9;
  int kc = rest % KC, m = rest / KC;
  int co = m * 16 + (l & 15);
  int k = kc * 32 + (l >> 4) * 8 + e;
  float w = 0.f;
  if (k < K && co < CO) {
    int ci, dy, dx;
    if (CL) {
      ci = k % CIN;
      int r = k / CIN;
      dy = r / KS;
      dx = r % KS;
    } else {
      ci = k / (KS * KS);
      int r = k % (KS * KS);
      dy = r / KS;
      dx = r % KS;
    }
    w = Wc[((co * CIN + ci) * KS + dy) * KS + dx];
  }
  unsigned b0 = rne_bf16_bits(w);
  float f0 = __uint_as_float(b0 << 16);
  float d1 = w - f0;
  unsigned b1 = rne_bf16_bits(d1);
  float f1 = __uint_as_float(b1 << 16);
  unsigned b2 = rne_bf16_bits(d1 - f1);
  Wm[i] = (ushort)b0;
  Wm[PLANE + i] = (ushort)b1;
  Wm[2 * PLANE + i] = (ushort)b2;
}

// ---------------- conv_mfma_d: direct store, NSUB n-tiles per wave (L1) --------
// Per (co,j) a wave stores NSUB adjacent 64-B runs back-to-back -> L2 merges.
template <int CIN, int HW, int KS, int PAD, int CO, int RS, int NW, int NSUB>
__global__ __launch_bounds__(NW * 64) void conv_mfma_d(const float* __restrict__ S,
                                                       const ushort* __restrict__ Wm,
                                                       float* __restrict__ U) {
  constexpr int PH = HW + 2 * PAD;
  constexpr int K = CIN * KS * KS;
  constexpr int KC = (K + 31) / 32;
  constexpr int MT = (CO + 15) / 16;
  constexpr int N = HW * HW;
  constexpr int NT = (N + 15) / 16;
  constexpr int NG = (NT + NSUB - 1) / NSUB;
  constexpr int TILE = CIN * PH * RS;
  constexpr int KPAD = KC * 32;
  __shared__ float lin[TILE];
  __shared__ int koff[KPAD];
  const int t = blockIdx.x, b = blockIdx.y, B = gridDim.y;
  const int tid = threadIdx.x;

  for (int i = tid; i < TILE; i += NW * 64) lin[i] = 0.f;
  for (int k = tid; k < KPAD; k += NW * 64) {
    int ci = k / (KS * KS), r = k % (KS * KS), dy = r / KS, dx = r % KS;
    koff[k] = (k < K) ? (ci * PH * RS + dy * RS + dx) : 0;
  }
  __syncthreads();
  const float* src = S + ((long)t * B + b) * (CIN * N);
  for (int i = tid; i < CIN * N; i += NW * 64) {
    int ci = i / N, r = i % N, iy = r / HW, ix = r % HW;
    lin[ci * PH * RS + (iy + PAD) * RS + ix + PAD] = src[i];
  }
  __syncthreads();

  const int lane = tid & 63;
  const int wv = tid >> 6;
  const int g = lane >> 4;
  const int col = lane & 15;

  bf16x8 af[3 * MT * KC];  // L1: 12 frags (48 VGPR)
#pragma unroll
  for (int f = 0; f < 3 * MT * KC; ++f)
    af[f] = *(const bf16x8*)(Wm + (long)f * 512 + lane * 8);

  for (int grp = wv; grp < NG; grp += NW) {
    const int px0 = grp * (16 * NSUB);
    bool vs[NSUB];
    int pxb[NSUB];
    bf16x8 bf[NSUB][KC];
#pragma unroll
    for (int s = 0; s < NSUB; ++s) {
      int px = px0 + s * 16 + col;
      vs[s] = px < N;
      int ppx = vs[s] ? px : 0;
      int y = ppx / HW, x = ppx % HW;
      pxb[s] = y * RS + x;
#pragma unroll
      for (int kc = 0; kc < KC; ++kc) {
        bf16x8 v;
#pragma unroll
        for (int e = 0; e < 8; ++e) {
          float val = lin[pxb[s] + koff[kc * 32 + g * 8 + e]];
          v[e] = (short)(__float_as_uint(val) >> 16);  // exact for 0/1
        }
        bf[s][kc] = v;
      }
    }

#pragma unroll
    for (int m = 0; m < MT; ++m) {
      f32x4 acc[NSUB];
#pragma unroll
      for (int s = 0; s < NSUB; ++s) acc[s] = (f32x4){0.f, 0.f, 0.f, 0.f};
#pragma unroll
      for (int p = 0; p < 3; ++p) {
#pragma unroll
        for (int kc = 0; kc < KC; ++kc) {
          bf16x8 a = af[(p * MT + m) * KC + kc];
#pragma unroll
          for (int s = 0; s < NSUB; ++s)
            acc[s] = __builtin_amdgcn_mfma_f32_16x16x32_bf16(a, bf[s][kc], acc[s], 0, 0, 0);
        }
      }
      const int co0 = m * 16 + g * 4;  // D row = g*4 + reg (r20-r27 verified)
#pragma unroll
      for (int s = 0; s < NSUB; ++s) {
        if (vs[s]) {
          float* up = U + (((long)t * B + b) * CO + co0) * N + px0 + s * 16 + col;
#pragma unroll
          for (int j = 0; j < 4; ++j)
            if (co0 + j < CO) up[(long)j * N] = acc[s][j];
        }
      }
    }
  }
}

// ---------------- conv_mfma_v: channel-last bf16 LDS, b128 B-frags (L3, L5) ----
// linb[pixel][ci] bf16 (CPAD stride): fragment (kc,g) = 16 contiguous bytes
// -> one ds_read_b128. offb[kc*4+g] = within-tile offset for the fragment.
// Rest = r27 conv_mfma_c: wave-owns-nt, bf[KC] resident, acc over ml/p/kc,
// cst LDS staging + float4 stream, chunks across gridDim.z.
template <int CIN, int HW, int KS, int PAD, int CO, int CPAD, int NW, int MCHUNK>
__global__ __launch_bounds__(NW * 64) void conv_mfma_v(const float* __restrict__ S,
                                                       const ushort* __restrict__ Wm,
                                                       float* __restrict__ U) {
  constexpr int PW = HW + 2 * PAD;
  constexpr int K = CIN * KS * KS;
  constexpr int KC = (K + 31) / 32;
  constexpr int KPAD = KC * 32;
  constexpr int RMAX = (KPAD - 1) / CIN;      // max taps row index accessed
  constexpr int DYMAX = RMAX / KS;
  constexpr int PHA = (HW + DYMAX > PW) ? (HW + DYMAX) : PW;  // zero rows absorb k>=K
  constexpr int MT = CO / 16;
  constexpr int N = HW * HW;
  constexpr int NT = (N + 15) / 16;
  constexpr int NCH = MT / MCHUNK;
  constexpr int CROWS = MCHUNK * 16;
  __shared__ ushort linb[PHA * PW * CPAD];
  __shared__ int offb[KC * 4];
  __shared__ float cst[CROWS * N];
  const int t = blockIdx.x, b = blockIdx.y, B = gridDim.y;
  const int tid = threadIdx.x;

  for (int i = tid; i < PHA * PW * CPAD / 2; i += NW * 64) ((int*)linb)[i] = 0;
  for (int i = tid; i < KC * 4; i += NW * 64) {
    int k0 = (i >> 2) * 32 + (i & 3) * 8;
    int ci0 = k0 % CIN, r0 = k0 / CIN;
    offb[i] = ((r0 / KS) * PW + (r0 % KS)) * CPAD + ci0;
  }
  __syncthreads();
  const float* src = S + ((long)t * B + b) * (CIN * N);
  for (int i = tid; i < CIN * N; i += NW * 64) {
    int ci = i / N, r = i % N, iy = r / HW, ix = r % HW;
    linb[((iy + PAD) * PW + ix + PAD) * CPAD + ci] =
        (ushort)(__float_as_uint(src[i]) >> 16);  // exact for 0/1
  }
  __syncthreads();

  const int lane = tid & 63;
  const int wv = tid >> 6;
  const int g = lane >> 4;
  const int col = lane & 15;

  int boff[KC];
#pragma unroll
  for (int kc = 0; kc < KC; ++kc) boff[kc] = offb[kc * 4 + g];

  for (int ch = blockIdx.z; ch < NCH; ch += gridDim.z) {
    for (int nt = wv; nt < NT; nt += NW) {
      int px = nt * 16 + col;
      bool vpx = px < N;
      int ppx = vpx ? px : 0;
      int y = ppx / HW, x = ppx % HW;
      const int pxb = (y * PW + x) * CPAD;

      bf16x8 bf[KC];
#pragma unroll
      for (int kc = 0; kc < KC; ++kc)
        bf[kc] = *(const bf16x8*)(linb + pxb + boff[kc]);  // 16B aligned

#pragma unroll
      for (int ml = 0; ml < MCHUNK; ++ml) {
        const int m = ch * MCHUNK + ml;
        f32x4 acc = {0.f, 0.f, 0.f, 0.f};
#pragma unroll
        for (int p = 0; p < 3; ++p) {
#pragma unroll
          for (int kc = 0; kc < KC; ++kc) {
            bf16x8 a = *(const bf16x8*)(Wm + ((long)(p * MT + m) * KC + kc) * 512 + lane * 8);
            acc = __builtin_amdgcn_mfma_f32_16x16x32_bf16(a, bf[kc], acc, 0, 0, 0);
          }
        }
        if (vpx) {
          const int r0 = ml * 16 + g * 4;  // D row = g*4 + reg (r20-r27 verified)
#pragma unroll
          for (int j = 0; j < 4; ++j) cst[(r0 + j) * N + px] = acc[j];
        }
      }
    }
    __syncthreads();
    // stream chunk (contiguous [CROWS][N] region of U) as float4
    const f32x4* cs = (const f32x4*)cst;
    f32x4* ug = (f32x4*)(U + (((long)t * B + b) * CO + ch * CROWS) * N);
    for (int i = tid; i < CROWS * N / 4; i += NW * 64) ug[i] = cs[i];
    __syncthreads();
  }
}

// ---------------- fused psp->pool(x11)->psp, 4 lanes/neuron, 4-deep prefetch ----------------
template <int C, int HIN, int HOUT>
__global__ __launch_bounds__(128) void ppp4_tm(const float* __restrict__ U,
                                               float* __restrict__ out, int B) {
  const int NOUT = B * C * HOUT * HOUT;
  const long SIN = (long)B * C * HIN * HIN;
  int id = blockIdx.x * 128 + threadIdx.x;
  int sub = id & 3, m = id >> 2;
  bool active = m < NOUT;
  int mm = active ? m : 0;
  int x2 = mm % HOUT;
  int y2 = (mm / HOUT) % HOUT;
  int c = (mm / (HOUT * HOUT)) % C;
  int b = mm / (C * HOUT * HOUT);
  int iy = 2 * y2 + (sub >> 1), ix = 2 * x2 + (sub & 1);
  bool valid = active && iy < HIN && ix < HIN;
  const float* base = U + ((long)(b * C + c) * HIN + iy) * HIN + ix;
  bool writer = active && (sub == 0);
  float* op = out + mm;
  IIR si, so;
  float pr0 = valid ? base[0] : 0.f;
  float pr1 = valid ? base[SIN] : 0.f;
  float pr2 = valid ? base[2 * SIN] : 0.f;
  float pr3 = valid ? base[3 * SIN] : 0.f;
  for (int tb = 0; tb < TT; tb += 4) {
    float a0 = pr0, a1 = pr1, a2 = pr2, a3 = pr3;
    const float* nb = base + (long)(tb + 4) * SIN;  // last iter overreads into ws
    pr0 = valid ? nb[0] : 0.f;
    pr1 = valid ? nb[SIN] : 0.f;
    pr2 = valid ? nb[2 * SIN] : 0.f;
    pr3 = valid ? nb[3 * SIN] : 0.f;
    {
      float s = si.step(a0);
      float v = s + __shfl_xor(s, 1); v += __shfl_xor(v, 2);
      float o = so.step(11.0f * v);
      if (writer) op[(long)tb * NOUT] = o;
    }
    {
      float s = si.step(a1);
      float v = s + __shfl_xor(s, 1); v += __shfl_xor(v, 2);
      float o = so.step(11.0f * v);
      if (writer) op[(long)(tb + 1) * NOUT] = o;
    }
    {
      float s = si.step(a2);
      float v = s + __shfl_xor(s, 1); v += __shfl_xor(v, 2);
      float o = so.step(11.0f * v);
      if (writer) op[(long)(tb + 2) * NOUT] = o;
    }
    {
      float s = si.step(a3);
      float v = s + __shfl_xor(s, 1); v += __shfl_xor(v, 2);
      float o = so.step(11.0f * v);
      if (writer) op[(long)(tb + 3) * NOUT] = o;
    }
  }
}

// ---------------- dense7k: split-k x8 GEMM, P[kz][row][o] partials ----------------
__global__ __launch_bounds__(256) void dense7k(const float* __restrict__ S,
                                               const float* __restrict__ Wt,
                                               float* __restrict__ P) {
  const int r0 = blockIdx.x * 16 + (threadIdx.x >> 6) * 4;
  const int kz = blockIdx.y;
  const int lane = threadIdx.x & 63;
  const float* s0 = S + (long)r0 * 2400;
  const float* s1 = s0 + 2400;
  const float* s2 = s0 + 4800;
  const float* s3 = s0 + 7200;
  const float* wp = Wt + lane * 4;
  v2f aA[4], aB[4];
#pragma unroll
  for (int o = 0; o < 4; ++o) { aA[o] = (v2f)(0.f); aB[o] = (v2f)(0.f); }
  const int k0 = kz * 300, k1 = k0 + 300;
  for (int k = k0; k < k1; k += 4) {
    float4 a0 = *(const float4*)(s0 + k);
    float4 a1 = *(const float4*)(s1 + k);
    float4 a2 = *(const float4*)(s2 + k);
    float4 a3 = *(const float4*)(s3 + k);
#define DSTEP(KK, AX)                                                        \
    {                                                                        \
      float4 w = *(const float4*)(wp + (long)(k + KK) * 256);                \
      v2f pA, pB;                                                            \
      pA.x = a0.AX; pA.y = a1.AX; pB.x = a2.AX; pB.y = a3.AX;                \
      aA[0] += pA * w.x; aA[1] += pA * w.y; aA[2] += pA * w.z; aA[3] += pA * w.w; \
      aB[0] += pB * w.x; aB[1] += pB * w.y; aB[2] += pB * w.z; aB[3] += pB * w.w; \
    }
    DSTEP(0, x) DSTEP(1, y) DSTEP(2, z) DSTEP(3, w)
#undef DSTEP
  }
  float* p = P + (long)kz * 307200 + (long)r0 * 256 + lane * 4;
#pragma unroll
  for (int o = 0; o < 4; ++o) p[o] = aA[o].x;
#pragma unroll
  for (int o = 0; o < 4; ++o) p[256 + o] = aA[o].y;
#pragma unroll
  for (int o = 0; o < 4; ++o) p[512 + o] = aB[o].x;
#pragma unroll
  for (int o = 0; o < 4; ++o) p[768 + o] = aB[o].y;
}

// ---------------- reduce8: U7 = sum of 8 partials (float4, ascending kz) ----------------
__global__ __launch_bounds__(256) void reduce8(const float* __restrict__ P,
                                               float* __restrict__ U7) {
  int i = blockIdx.x * 256 + threadIdx.x;  // over 76800 float4s
  if (i >= 76800) return;
  const float4* p = (const float4*)P;
  float4 a = p[i];
#pragma unroll
  for (int kz = 1; kz < 8; ++kz) {
    float4 b = p[(long)kz * 76800 + i];
    a.x += b.x; a.y += b.y; a.z += b.z; a.w += b.w;
  }
  ((float4*)U7)[i] = a;
}

// ---------------- psp7: psp+spike over U7, 4-deep prefetch ----------------
__global__ __launch_bounds__(128) void psp7(const float* __restrict__ U7,
                                            float* __restrict__ out) {
  int n = blockIdx.x * 128 + threadIdx.x;  // 0..1023
  IIR st;
  float pr0 = U7[n], pr1 = U7[1024 + n], pr2 = U7[2048 + n], pr3 = U7[3072 + n];
  for (int tb = 0; tb < TT; tb += 4) {
    float a0 = pr0, a1 = pr1, a2 = pr2, a3 = pr3;
    const float* nb = U7 + (long)(tb + 4) * 1024 + n;  // overreads into ws at end
    pr0 = nb[0]; pr1 = nb[1024]; pr2 = nb[2048]; pr3 = nb[3072];
    out[(long)tb * 1024 + n] = st.step(a0);
    out[(long)(tb + 1) * 1024 + n] = st.step(a1);
    out[(long)(tb + 2) * 1024 + n] = st.step(a2);
    out[(long)(tb + 3) * 1024 + n] = st.step(a3);
  }
}

// ---------------- dense8 ----------------
__global__ __launch_bounds__(256) void dense8(const float* __restrict__ S,
                                              const float* __restrict__ W,
                                              float* __restrict__ U) {
  int id = blockIdx.x * 256 + threadIdx.x;
  if (id >= 12000) return;
  int o = id % 10, row = id / 10;
  const float* sr = S + (long)row * 256;
  const float* wr = W + o * 256;
  float acc = 0.f;
  for (int k = 0; k < 256; k += 4) {
    float4 a = *(const float4*)(sr + k);
    float4 w = *(const float4*)(wr + k);
    acc += a.x * w.x; acc += a.y * w.y; acc += a.z * w.z; acc += a.w * w.w;
  }
  U[id] = acc;
}

// ---------------- final psp+spike + transpose to (B,10,T), prefetched ----------------
__global__ void psp8_out(const float* __restrict__ U, float* __restrict__ out) {
  int n = threadIdx.x;
  bool act = n < 40;
  int nn = act ? n : 0;
  IIR st;
  float pr0 = U[nn], pr1 = U[40 + nn], pr2 = U[80 + nn], pr3 = U[120 + nn];
  for (int tb = 0; tb < TT; tb += 4) {
    float a0 = pr0, a1 = pr1, a2 = pr2, a3 = pr3;
    const float* nb = U + (long)(tb + 4) * 40 + nn;  // overreads into ws at end
    pr0 = nb[0]; pr1 = nb[40]; pr2 = nb[80]; pr3 = nb[120];
    float o0 = st.step(a0), o1 = st.step(a1), o2 = st.step(a2), o3 = st.step(a3);
    if (act) {
      out[nn * TT + tb] = o0;
      out[nn * TT + tb + 1] = o1;
      out[nn * TT + tb + 2] = o2;
      out[nn * TT + tb + 3] = o3;
    }
  }
}

extern "C" void kernel_launch(void* const* d_in, const int* in_sizes, int n_in,
                              void* d_out, int out_size, void* d_ws, size_t ws_size,
                              hipStream_t stream) {
  const float* s_in = (const float*)d_in[0];
  const float* Wc1  = (const float*)d_in[1];
  const float* Wc2  = (const float*)d_in[2];
  const float* Wc3  = (const float*)d_in[3];
  const float* Wd4a = (const float*)d_in[4];
  const float* Wd4b = (const float*)d_in[5];

  float* Buf1 = (float*)d_ws;            // 33,292,800 floats (U1/U3/U5)
  float* Buf2 = Buf1 + 33292800;
  float* s2   = Buf2;                    //  8,323,200
  float* s4   = Buf2 + 8323200;          //  4,665,600
  float* Wt4a = Buf2 + 12988800;         //    614,400
  float* T0   = Buf2 + 13910400;         //  2,774,400
  float* s7   = Buf2 + 16737840;         //    307,200
  float* P7   = Buf2 + 17045040;         //  2,457,600 (8 x 307,200 partials)
  float* U7   = Buf2 + 19502640;         //    307,200
  float* s6   = Buf2;                    //  2,880,000 (s2 region, dead by L6)
  float* U8   = Buf1;                    //     12,000 (Buf1 dead by L8)
  // MFMA weight planes live in P7's region (first written by dense7k, which
  // runs after every conv has finished reading Wm -- stream-ordered).
  ushort* Wm1 = (ushort*)P7;             //  18,432 ushorts (3 x 2m x 2kc x 512)
  ushort* Wm2 = Wm1 + 18432;             //  32,256 ushorts (3 x 3m x 7kc x 512)
  ushort* Wm3 = Wm1 + 50688;             // 129,024 ushorts (3 x 6m x 14kc x 512)

  // prep: input -> time-major; Wd4a -> [k][o]; conv weights -> MFMA planes
  transpose_rc<<<dim3(5, 145), 256, 0, stream>>>(s_in, T0, 9248, 300);
  transpose_rc<<<dim3(38, 4), 256, 0, stream>>>(Wd4a, Wt4a, 256, 2400);
  prep_mfma<2, 5, 24, 2, 2, 0><<<24, 256, 0, stream>>>(Wc1, Wm1);
  prep_mfma<24, 3, 48, 3, 7, 1><<<42, 256, 0, stream>>>(Wc2, Wm2);
  prep_mfma<48, 3, 96, 6, 14, 1><<<168, 256, 0, stream>>>(Wc3, Wm3);

  // L1: conv 2->24 k5 p2, MFMA direct store (NSUB=4 -> 256-B runs per co)
  conv_mfma_d<2, 34, 5, 2, 24, 39, 8, 4><<<dim3(300, 4), 512, 0, stream>>>(T0, Wm1, Buf1);
  // L1-psp + pool 34->17 + psp -> s2
  ppp4_tm<24, 34, 17><<<867, 128, 0, stream>>>(Buf1, s2, 4);
  // L3: conv 24->48 k3 p1, channel-last b128 B (CPAD=24; 3 chunks; ~37KB LDS)
  conv_mfma_v<24, 17, 3, 1, 48, 24, 8, 1><<<dim3(300, 4), 512, 0, stream>>>(s2, Wm2, Buf1);
  // L3-psp + pool 17->9 + psp -> s4
  ppp4_tm<48, 17, 9><<<486, 128, 0, stream>>>(Buf1, s4, 4);
  // L5: conv 48->96 k3 p1, channel-last b128 B (CPAD=56; z=2 chunks; ~31KB LDS)
  conv_mfma_v<48, 9, 3, 1, 96, 56, 6, 3><<<dim3(300, 4, 2), 384, 0, stream>>>(s4, Wm3, Buf1);
  // L5-psp + pool 9->5 + psp -> s6
  ppp4_tm<96, 9, 5><<<300, 128, 0, stream>>>(Buf1, s6, 4);
  // L7: dense 2400->256 split-k x8 ; fold partials ; psp -> s7
  dense7k<<<dim3(75, 8), 256, 0, stream>>>(s6, Wt4a, P7);
  reduce8<<<300, 256, 0, stream>>>(P7, U7);
  psp7<<<8, 128, 0, stream>>>(U7, s7);
  // L8: dense 256->10 ; psp + output transpose
  dense8<<<47, 256, 0, stream>>>(s7, Wd4b, U8);
  psp8_out<<<1, 64, 0, stream>>>(U8, (float*)d_out);
}